// Round 11
// baseline (183.920 us; speedup 1.0000x reference)
//
#include <hip/hip_runtime.h>
#include <stdint.h>

// ContinuousConvolution, MI355X gfx950. Round 11: fused pipeline.
//   memset -> pack_count -> scan_scatter -> fused knn+mlp  (4 dispatches).
// Fused kernel: per 1-wave block, 4 sorted-order queries: grid-KNN (R9-exact,
// indices stay in registers) then collapsed-linear MLP (R10-exact math).
// All arithmetic expressions byte-identical to R10 -> same absmax.

typedef unsigned short u16;
typedef unsigned int   u32;
typedef unsigned long long u64;

#define NPTS  8192
#define KNB   16
#define SCAP  128

__device__ __forceinline__ float bf2f(u16 u) {
    union { u32 i; float f; } v; v.i = ((u32)u) << 16; return v.f;
}
__device__ __forceinline__ u16 f2bf(float f) {
    u32 x = __float_as_uint(f);
    return (u16)((x + 0x7FFFu + ((x >> 16) & 1u)) >> 16);  // RNE (lossless here)
}
__device__ __forceinline__ u32 fordkey(float f) {
    u32 u = __float_as_uint(f);
    return u ^ ((u32)((int)u >> 31) | 0x80000000u);
}
__device__ __forceinline__ u64 shflxor64(u64 v, int m) {
    int lo = __shfl_xor((int)(u32)v, m, 64);
    int hi = __shfl_xor((int)(u32)(v >> 32), m, 64);
    return ((u64)(u32)hi << 32) | (u32)lo;
}
// Reference-matching d2 (verified round 5): dot = Eigen FMA chain, rest strict.
__device__ __forceinline__ float sq_np32(float x, float y, float z) {
    return __fadd_rn(__fadd_rn(__fmul_rn(x, x), __fmul_rn(y, y)), __fmul_rn(z, z));
}
__device__ __forceinline__ float d2_ref(float qx, float qy, float qz, float qsq,
                                        float x, float y, float z, float sq) {
    float dot = fmaf(z, qz, fmaf(y, qy, __fmul_rn(x, qx)));
    return __fsub_rn(__fadd_rn(qsq, sq), __fmul_rn(2.0f, dot));
}
__device__ __forceinline__ int cellof(float v) {
    int c = (int)floorf(v * 8.0f);
    return c < 0 ? 0 : (c > 7 ? 7 : c);
}

// ---------------- Kernel 1: pack + count ----------------
__global__ __launch_bounds__(256) void pack_count_kernel(
    const float* __restrict__ pf, const float* __restrict__ coords,
    u16* __restrict__ pfh, int* __restrict__ counts) {
    int gid = blockIdx.x * 256 + threadIdx.x;     // 0..1048575
    pfh[gid] = f2bf(pf[gid]);
    if (gid < 2 * NPTS) {
        float x = coords[gid * 3 + 0];
        float y = coords[gid * 3 + 1];
        float z = coords[gid * 3 + 2];
        int b = gid >> 13;
        int cell = (cellof(x) * 8 + cellof(y)) * 8 + cellof(z);
        atomicAdd(&counts[b * 512 + cell], 1);
    }
}

// ---------------- Kernel 2: scan + scatter (fused) ----------------
// 2 blocks (one per batch) x 512 threads. LDS scan of 512 cell counts, then
// LDS-atomic scatter of the batch's 8192 points into sorted order.
__global__ __launch_bounds__(512) void scan_scatter_kernel(
    const int* __restrict__ counts, const float* __restrict__ coords,
    int* __restrict__ cellStart, float4* __restrict__ spts,
    int* __restrict__ sidx) {
    __shared__ int s[512];
    __shared__ int off[512];
    int b = blockIdx.x, t = threadIdx.x;
    int myc = counts[b * 512 + t];
    s[t] = myc; __syncthreads();
#pragma unroll
    for (int o = 1; o < 512; o <<= 1) {
        int v = (t >= o) ? s[t - o] : 0; __syncthreads();
        s[t] += v; __syncthreads();
    }
    int excl = s[t] - myc;
    cellStart[b * 513 + t] = excl;
    off[t] = excl;
    if (t == 511) cellStart[b * 513 + 512] = s[511];
    __syncthreads();

    const float* cb = coords + (size_t)b * NPTS * 3;
#pragma unroll 1
    for (int k = 0; k < 16; ++k) {
        int i = k * 512 + t;                 // 0..8191, coalesced reads
        float x = cb[i * 3 + 0];
        float y = cb[i * 3 + 1];
        float z = cb[i * 3 + 2];
        int cell = (cellof(x) * 8 + cellof(y)) * 8 + cellof(z);
        int pos = atomicAdd(&off[cell], 1);
        spts[b * NPTS + pos] = make_float4(x, y, z, sq_np32(x, y, z));
        sidx[b * NPTS + pos] = i;
    }
}

// ---------------- Kernel 3: fused knn + mlp ----------------
// 1 wave per block, 4 queries per block, sorted order + XCD chunk swizzle.
__global__ __launch_bounds__(64) void knnmlp_kernel(
    const float* __restrict__ coords, const float4* __restrict__ spts,
    const int* __restrict__ sidx, const int* __restrict__ cellStart,
    const u16* __restrict__ pfh,
    const float* __restrict__ w1, const float* __restrict__ b1,
    const float* __restrict__ w2, const float* __restrict__ b2,
    const float* __restrict__ w3, const float* __restrict__ b3,
    const float* __restrict__ aw, const float* __restrict__ ab,
    float* __restrict__ out) {
    __shared__ u64 surv[SCAP];
    __shared__ __attribute__((aligned(16))) float vbuf[2][68];
    __shared__ __attribute__((aligned(16))) float h1buf[2][36];

    const int lane = threadIdx.x;
    // XCD chunk swizzle: grid 4096 = 8 XCDs x 512 contiguous sorted chunks
    const int sblk = (blockIdx.x & 7) * 512 + (blockIdx.x >> 3);
    const int b    = sblk >> 11;               // 2048 blocks per batch
    const int p0   = (sblk & 2047) * 4;        // sorted position of query 0
    const float*  cb = coords + (size_t)b * NPTS * 3;
    const float4* sp = spts + b * NPTS;
    const int*    si = sidx + b * NPTS;
    const int*    cs = cellStart + b * 513;

    int qarr[4];                               // original query ids
    int midx[4];                               // lane<16: my neighbor idx

    // ---------------- phase 1: KNN for 4 queries (R9-exact) ----------------
#pragma unroll 1
    for (int t = 0; t < 4; ++t) {
        const int q = si[p0 + t];              // sorted order
        qarr[t] = q;
        float qx = cb[q * 3 + 0], qy = cb[q * 3 + 1], qz = cb[q * 3 + 2];
        float qsq = sq_np32(qx, qy, qz);
        int cqx = cellof(qx), cqy = cellof(qy), cqz = cellof(qz);

        // PASS A: lane-minima over 3^3 cell box -> conservative tau
        int ax0 = max(cqx - 1, 0), ax1 = min(cqx + 1, 7);
        int ay0 = max(cqy - 1, 0), ay1 = min(cqy + 1, 7);
        int az0 = max(cqz - 1, 0), az1 = min(cqz + 1, 7);
        float dmin = 3.0e38f;
#pragma unroll 1
        for (int cx = ax0; cx <= ax1; ++cx)
#pragma unroll 1
            for (int cy = ay0; cy <= ay1; ++cy) {
                int base = (cx * 8 + cy) * 8;
                int s = cs[base + az0], e = cs[base + az1 + 1];
                for (int i0 = s; i0 < e; i0 += 64) {
                    int i = i0 + lane;
                    int ii = (i < e) ? i : (e - 1);
                    float4 c = sp[ii];
                    float d2 = d2_ref(qx, qy, qz, qsq, c.x, c.y, c.z, c.w);
                    if (i < e) dmin = fminf(dmin, d2);
                }
            }
        {   // wave bitonic sort-64 ascending
            float v = dmin;
#pragma unroll
            for (int k = 2; k <= 64; k <<= 1) {
#pragma unroll
                for (int j2 = k >> 1; j2 >= 1; j2 >>= 1) {
                    float o = __shfl_xor(v, j2, 64);
                    bool lo = (lane & j2) == 0;
                    bool up = (lane & k) == 0;
                    float mn = fminf(v, o), mx = fmaxf(v, o);
                    v = (lo == up) ? mn : mx;
                }
            }
            dmin = __shfl(v, 15, 64);
        }
        const float tau = dmin;                 // >= true 16th-NN d2

        // PASS B: wave-uniform filter scan, d2 <= tau
        float rr = sqrtf(tau + 1e-5f) + 1e-6f;
        int bx0 = max((int)floorf((qx - rr) * 8.0f), 0);
        int bx1 = min((int)floorf((qx + rr) * 8.0f), 7);
        int by0 = max((int)floorf((qy - rr) * 8.0f), 0);
        int by1 = min((int)floorf((qy + rr) * 8.0f), 7);
        int bz0 = max((int)floorf((qz - rr) * 8.0f), 0);
        int bz1 = min((int)floorf((qz + rr) * 8.0f), 7);
        int cnt = 0;
#pragma unroll 1
        for (int cx = bx0; cx <= bx1; ++cx)
#pragma unroll 1
            for (int cy = by0; cy <= by1; ++cy) {
                int base = (cx * 8 + cy) * 8;
                int s = cs[base + bz0], e = cs[base + bz1 + 1];
                for (int i0 = s; i0 < e; i0 += 64) {
                    int i = i0 + lane;
                    bool valid = (i < e);
                    int ii = valid ? i : (e - 1);
                    float4 c = sp[ii];
                    float d2 = d2_ref(qx, qy, qz, qsq, c.x, c.y, c.z, c.w);
                    bool pass = valid && (d2 <= tau);
                    u64 mask = __ballot(pass);
                    if (pass) {
                        int pre = __builtin_amdgcn_mbcnt_hi((u32)(mask >> 32),
                                  __builtin_amdgcn_mbcnt_lo((u32)mask, 0));
                        int pos = cnt + pre;
                        if (pos < SCAP)
                            surv[pos] = ((u64)fordkey(d2) << 32) | (u32)si[ii];
                    }
                    cnt += (int)__popcll(mask);
                }
            }
        __syncthreads();

        int myidx = 0;
        if (cnt <= 64) {
            u64 key = (lane < cnt) ? surv[lane] : ~0ull;
#pragma unroll
            for (int k = 2; k <= 64; k <<= 1) {
#pragma unroll
                for (int j2 = k >> 1; j2 >= 1; j2 >>= 1) {
                    u64 o = shflxor64(key, j2);
                    bool lo = (lane & j2) == 0;
                    bool up = (lane & k) == 0;
                    bool takemin = (lo == up);
                    key = ((o < key) == takemin) ? o : key;
                }
            }
            myidx = (int)(u32)(key & 0xffffffffu);
        } else {
            int cc = cnt > SCAP ? SCAP : cnt;
            u64 a0 = (lane < cc) ? surv[lane] : ~0ull;
            u64 a1 = (64 + lane < cc) ? surv[64 + lane] : ~0ull;
            if (a1 < a0) { u64 tmp = a0; a0 = a1; a1 = tmp; }
#pragma unroll 1
            for (int r = 0; r < 16; ++r) {
                u64 m = a0;
#pragma unroll
                for (int d = 1; d < 64; d <<= 1) {
                    u64 o = shflxor64(m, d);
                    m = (o < m) ? o : m;
                }
                if (a0 == m) { a0 = a1; a1 = ~0ull; }
                if (lane == r) myidx = (int)(u32)(m & 0xffffffffu);
            }
        }
        midx[t] = myidx;
        __syncthreads();   // surv reuse across t
    }

    __builtin_amdgcn_sched_barrier(0);  // keep weight loads out of knn phase

    // ---------------- phase 2: MLP for the same 4 queries (R10-exact) --------
    const int r   = lane & 31;
    const int vec = lane >> 5;
    float w1r[68];
#pragma unroll
    for (int c = 0; c < 67; ++c) w1r[c] = w1[r * 67 + c];
    w1r[67] = 0.0f;
    float w2r[32];
    {
        const float4* p = (const float4*)(w2 + lane * 32);
#pragma unroll
        for (int c4 = 0; c4 < 8; ++c4) {
            float4 v = p[c4];
            w2r[c4 * 4 + 0] = v.x; w2r[c4 * 4 + 1] = v.y;
            w2r[c4 * 4 + 2] = v.z; w2r[c4 * 4 + 3] = v.w;
        }
    }
    float w3r[64];
    {
        const float4* p = (const float4*)(w3 + lane * 64);
#pragma unroll
        for (int c4 = 0; c4 < 16; ++c4) {
            float4 v = p[c4];
            w3r[c4 * 4 + 0] = v.x; w3r[c4 * 4 + 1] = v.y;
            w3r[c4 * 4 + 2] = v.z; w3r[c4 * 4 + 3] = v.w;
        }
    }
    float awr[16];
#pragma unroll
    for (int k = 0; k < 16; ++k) awr[k] = aw[k];
    float sa = 0.0f;
#pragma unroll
    for (int k = 0; k < 16; ++k) sa += awr[k];
    const float b1v = b1[r], b2v = b2[lane], b3v = b3[lane], abv = ab[0];
    const float c1 = (vec == 0) ? 16.0f : sa;
    const u16* pfb = pfh + (size_t)b * NPTS * 64;

#pragma unroll 1
    for (int t = 0; t < 4; ++t) {
        const int gq = b * NPTS + qarr[t];
        int myi = __shfl(midx[t], lane & 15, 64);

        float pool = -3.0e38f, G1 = 0.0f, Ga = 0.0f;
#pragma unroll
        for (int k = 0; k < 16; ++k) {
            int nk = __shfl(myi, k, 64);
            float v = bf2f(pfb[nk * 64 + lane]);
            pool = fmaxf(pool, v);
            G1 += v;
            Ga = fmaf(awr[k], v, Ga);
        }
        vbuf[0][lane] = G1;
        vbuf[1][lane] = Ga;

        if (lane < 48) {
            int j  = lane >> 4;
            int i0 = __shfl(myi, 0, 64);
            float rel  = cb[myi * 3 + j] - cb[i0 * 3 + j];
            float wrel = awr[lane & 15] * rel;
#pragma unroll
            for (int d = 1; d < 16; d <<= 1) {
                rel  += __shfl_xor(rel, d, 64);
                wrel += __shfl_xor(wrel, d, 64);
            }
            if ((lane & 15) == 0) { vbuf[0][64 + j] = rel; vbuf[1][64 + j] = wrel; }
        }
        if (lane == 0) { vbuf[0][67] = 0.0f; vbuf[1][67] = 0.0f; }
        __syncthreads();

        float acc = c1 * b1v;
        {
            const float4* vp = (const float4*)(&vbuf[vec][0]);
#pragma unroll
            for (int c4 = 0; c4 < 17; ++c4) {
                float4 g4 = vp[c4];
                acc = fmaf(g4.x, w1r[c4 * 4 + 0], acc);
                acc = fmaf(g4.y, w1r[c4 * 4 + 1], acc);
                acc = fmaf(g4.z, w1r[c4 * 4 + 2], acc);
                acc = fmaf(g4.w, w1r[c4 * 4 + 3], acc);
            }
        }
        h1buf[vec][r] = acc;
        __syncthreads();

        float a0 = 16.0f * b2v, a1 = sa * b2v;
        {
            const float4* p0 = (const float4*)(&h1buf[0][0]);
            const float4* p1 = (const float4*)(&h1buf[1][0]);
#pragma unroll
            for (int c4 = 0; c4 < 8; ++c4) {
                float4 x0 = p0[c4], x1 = p1[c4];
                a0 = fmaf(x0.x, w2r[c4 * 4 + 0], a0);
                a0 = fmaf(x0.y, w2r[c4 * 4 + 1], a0);
                a0 = fmaf(x0.z, w2r[c4 * 4 + 2], a0);
                a0 = fmaf(x0.w, w2r[c4 * 4 + 3], a0);
                a1 = fmaf(x1.x, w2r[c4 * 4 + 0], a1);
                a1 = fmaf(x1.y, w2r[c4 * 4 + 1], a1);
                a1 = fmaf(x1.z, w2r[c4 * 4 + 2], a1);
                a1 = fmaf(x1.w, w2r[c4 * 4 + 3], a1);
            }
        }
        __syncthreads();
        vbuf[0][lane] = a0;
        vbuf[1][lane] = a1;
        __syncthreads();

        float s1 = 16.0f * b3v, sA = sa * b3v;
        {
            const float4* p0 = (const float4*)(&vbuf[0][0]);
            const float4* p1 = (const float4*)(&vbuf[1][0]);
#pragma unroll
            for (int c4 = 0; c4 < 16; ++c4) {
                float4 x0 = p0[c4], x1 = p1[c4];
                s1 = fmaf(x0.x, w3r[c4 * 4 + 0], s1);
                s1 = fmaf(x0.y, w3r[c4 * 4 + 1], s1);
                s1 = fmaf(x0.z, w3r[c4 * 4 + 2], s1);
                s1 = fmaf(x0.w, w3r[c4 * 4 + 3], s1);
                sA = fmaf(x1.x, w3r[c4 * 4 + 0], sA);
                sA = fmaf(x1.y, w3r[c4 * 4 + 1], sA);
                sA = fmaf(x1.z, w3r[c4 * 4 + 2], sA);
                sA = fmaf(x1.w, w3r[c4 * 4 + 3], sA);
            }
        }
        float* op = out + (size_t)gq * 192;
        op[lane]       = s1;
        op[64 + lane]  = pool;
        op[128 + lane] = sA + abv;
        __syncthreads();
    }
}

extern "C" void kernel_launch(void* const* d_in, const int* in_sizes, int n_in,
                              void* d_out, int out_size, void* d_ws, size_t ws_size,
                              hipStream_t stream) {
    const float* pf     = (const float*)d_in[0];
    const float* coords = (const float*)d_in[1];
    const float* w1     = (const float*)d_in[2];
    const float* b1     = (const float*)d_in[3];
    const float* w2     = (const float*)d_in[4];
    const float* b2     = (const float*)d_in[5];
    const float* w3     = (const float*)d_in[6];
    const float* b3     = (const float*)d_in[7];
    const float* aw     = (const float*)d_in[8];
    const float* ab     = (const float*)d_in[9];

    char* ws = (char*)d_ws;
    u16*    pfh        = (u16*)ws;                              // 2 MB
    float4* spts       = (float4*)(ws + (2 << 20));             // 256 KB
    int*    sidx       = (int*)(ws + (2 << 20) + (256 << 10));  // 64 KB
    int*    cellStart  = (int*)(ws + (2 << 20) + (320 << 10));  // 2*513*4 B
    int*    counts     = (int*)(ws + (2 << 20) + (328 << 10));  // 2*512*4 B
    float*  outp       = (float*)d_out;

    hipMemsetAsync(counts, 0, 2 * 512 * sizeof(int), stream);
    pack_count_kernel<<<4096, 256, 0, stream>>>(pf, coords, pfh, counts);
    scan_scatter_kernel<<<2, 512, 0, stream>>>(counts, coords, cellStart,
                                               spts, sidx);
    knnmlp_kernel<<<4096, 64, 0, stream>>>(coords, spts, sidx, cellStart, pfh,
                                           w1, b1, w2, b2, w3, b3, aw, ab, outp);
}

// Round 12
// 181.661 us; speedup vs baseline: 1.0124x; 1.0124x over previous
//
#include <hip/hip_runtime.h>
#include <stdint.h>

// ContinuousConvolution, MI355X gfx950. Round 12:
//  - revert scan/scatter to the fast R9 pair (R11 collapsed scatter to 2 blocks: own goal)
//  - cell-centric fused knn+mlp: 1 block = 1 grid cell (256 thr / 4 waves);
//    3x3x3 candidate box staged to LDS once, reused by the cell's ~16 queries.
//    PASS A/B scan LDS (short dep chains) with provably-exact global fallback.
//    Per-wave surv/vbuf/h1buf + wave-local fences; one __syncthreads (staging).

typedef unsigned short u16;
typedef unsigned int   u32;
typedef unsigned long long u64;

#define NPTS  8192
#define KNB   16
#define SCAP  128
#define CAP   1024   // staged box capacity (E~432, +28 sigma)

__device__ __forceinline__ float bf2f(u16 u) {
    union { u32 i; float f; } v; v.i = ((u32)u) << 16; return v.f;
}
__device__ __forceinline__ u16 f2bf(float f) {
    u32 x = __float_as_uint(f);
    return (u16)((x + 0x7FFFu + ((x >> 16) & 1u)) >> 16);  // RNE (lossless here)
}
__device__ __forceinline__ u32 fordkey(float f) {
    u32 u = __float_as_uint(f);
    return u ^ ((u32)((int)u >> 31) | 0x80000000u);
}
__device__ __forceinline__ u64 shflxor64(u64 v, int m) {
    int lo = __shfl_xor((int)(u32)v, m, 64);
    int hi = __shfl_xor((int)(u32)(v >> 32), m, 64);
    return ((u64)(u32)hi << 32) | (u32)lo;
}
// Reference-matching d2 (verified round 5): dot = Eigen FMA chain, rest strict.
__device__ __forceinline__ float sq_np32(float x, float y, float z) {
    return __fadd_rn(__fadd_rn(__fmul_rn(x, x), __fmul_rn(y, y)), __fmul_rn(z, z));
}
__device__ __forceinline__ float d2_ref(float qx, float qy, float qz, float qsq,
                                        float x, float y, float z, float sq) {
    float dot = fmaf(z, qz, fmaf(y, qy, __fmul_rn(x, qx)));
    return __fsub_rn(__fadd_rn(qsq, sq), __fmul_rn(2.0f, dot));
}
__device__ __forceinline__ int cellof(float v) {
    int c = (int)floorf(v * 8.0f);
    return c < 0 ? 0 : (c > 7 ? 7 : c);
}

// ---------------- Kernel 1: pack + count ----------------
__global__ __launch_bounds__(256) void pack_count_kernel(
    const float* __restrict__ pf, const float* __restrict__ coords,
    u16* __restrict__ pfh, int* __restrict__ counts) {
    int gid = blockIdx.x * 256 + threadIdx.x;     // 0..1048575
    pfh[gid] = f2bf(pf[gid]);
    if (gid < 2 * NPTS) {
        float x = coords[gid * 3 + 0];
        float y = coords[gid * 3 + 1];
        float z = coords[gid * 3 + 2];
        int b = gid >> 13;
        int cell = (cellof(x) * 8 + cellof(y)) * 8 + cellof(z);
        atomicAdd(&counts[b * 512 + cell], 1);
    }
}

// ---------------- Kernel 2: scan ----------------
__global__ __launch_bounds__(512) void scan_kernel(
    const int* __restrict__ counts, int* __restrict__ cellStart,
    int* __restrict__ cellOffset) {
    __shared__ int s[512];
    int b = blockIdx.x, t = threadIdx.x;
    int myc = counts[b * 512 + t];
    s[t] = myc; __syncthreads();
#pragma unroll
    for (int o = 1; o < 512; o <<= 1) {
        int v = (t >= o) ? s[t - o] : 0; __syncthreads();
        s[t] += v; __syncthreads();
    }
    int excl = s[t] - myc;
    cellStart[b * 513 + t] = excl;
    cellOffset[b * 512 + t] = excl;
    if (t == 511) cellStart[b * 513 + 512] = s[511];
}

// ---------------- Kernel 3: scatter (64 blocks, global atomics) ----------------
__global__ __launch_bounds__(256) void scatter_kernel(
    const float* __restrict__ coords, int* __restrict__ cellOffset,
    float4* __restrict__ spts, int* __restrict__ sidx) {
    int gid = blockIdx.x * 256 + threadIdx.x;     // 0..16383
    float x = coords[gid * 3 + 0];
    float y = coords[gid * 3 + 1];
    float z = coords[gid * 3 + 2];
    int b = gid >> 13, i = gid & (NPTS - 1);
    int cell = (cellof(x) * 8 + cellof(y)) * 8 + cellof(z);
    int pos = atomicAdd(&cellOffset[b * 512 + cell], 1);
    spts[b * NPTS + pos] = make_float4(x, y, z, sq_np32(x, y, z));
    sidx[b * NPTS + pos] = i;
}

// ---------------- Kernel 4: fused cell-centric knn + mlp ----------------
// grid 1024 = 2 batches x 512 cells; 256 threads = 4 waves; each wave handles
// every 4th query of the cell (queries are the cell's own points).
__global__ __launch_bounds__(256) void knnmlp_kernel(
    const float* __restrict__ coords, const float4* __restrict__ spts,
    const int* __restrict__ sidx, const int* __restrict__ cellStart,
    const u16* __restrict__ pfh,
    const float* __restrict__ w1, const float* __restrict__ b1,
    const float* __restrict__ w2, const float* __restrict__ b2,
    const float* __restrict__ w3, const float* __restrict__ b3,
    const float* __restrict__ aw, const float* __restrict__ ab,
    float* __restrict__ out) {

    __shared__ __attribute__((aligned(16))) float4 bpts[CAP];
    __shared__ int bidx[CAP];
    __shared__ u64 surv[4][SCAP];
    __shared__ __attribute__((aligned(16))) float vbuf[4][2][68];
    __shared__ __attribute__((aligned(16))) float h1buf[4][2][36];

    const int tid  = threadIdx.x;
    const int lane = tid & 63;
    const int wv   = tid >> 6;
    const int cell = blockIdx.x & 511;
    const int b    = blockIdx.x >> 9;
    const float*  cb = coords + (size_t)b * NPTS * 3;
    const float4* sp = spts + b * NPTS;
    const int*    si = sidx + b * NPTS;
    const int*    cs = cellStart + b * 513;

    const int qs = cs[cell], qe = cs[cell + 1];
    const int m  = qe - qs;
    if (m == 0) return;                       // block-uniform

    const int cqx = cell >> 6, cqy = (cell >> 3) & 7, cqz = cell & 7;
    const int ax0 = max(cqx - 1, 0), ax1 = min(cqx + 1, 7);
    const int ay0 = max(cqy - 1, 0), ay1 = min(cqy + 1, 7);
    const int az0 = max(cqz - 1, 0), az1 = min(cqz + 1, 7);

    // total box count (uniform scalar math)
    int total = 0;
#pragma unroll 1
    for (int cx = ax0; cx <= ax1; ++cx)
#pragma unroll 1
        for (int cy = ay0; cy <= ay1; ++cy) {
            int base = (cx * 8 + cy) * 8;
            total += cs[base + az1 + 1] - cs[base + az0];
        }
    const bool stagedOK = (total <= CAP);
    const int  nBox = total;

    if (stagedOK) {                           // cooperative stage box -> LDS
        int acc = 0;
#pragma unroll 1
        for (int cx = ax0; cx <= ax1; ++cx)
#pragma unroll 1
            for (int cy = ay0; cy <= ay1; ++cy) {
                int base = (cx * 8 + cy) * 8;
                int s = cs[base + az0], e = cs[base + az1 + 1];
                for (int i = s + tid; i < e; i += 256) {
                    bpts[acc + i - s] = sp[i];
                    bidx[acc + i - s] = si[i];
                }
                acc += e - s;
            }
    }
    __syncthreads();                          // the only block barrier

    // MLP weights (per lane; identical across waves)
    const int r   = lane & 31;
    const int vec = lane >> 5;
    float w1r[68];
#pragma unroll
    for (int c = 0; c < 67; ++c) w1r[c] = w1[r * 67 + c];
    w1r[67] = 0.0f;
    float w2r[32];
    {
        const float4* p = (const float4*)(w2 + lane * 32);
#pragma unroll
        for (int c4 = 0; c4 < 8; ++c4) {
            float4 v = p[c4];
            w2r[c4 * 4 + 0] = v.x; w2r[c4 * 4 + 1] = v.y;
            w2r[c4 * 4 + 2] = v.z; w2r[c4 * 4 + 3] = v.w;
        }
    }
    float w3r[64];
    {
        const float4* p = (const float4*)(w3 + lane * 64);
#pragma unroll
        for (int c4 = 0; c4 < 16; ++c4) {
            float4 v = p[c4];
            w3r[c4 * 4 + 0] = v.x; w3r[c4 * 4 + 1] = v.y;
            w3r[c4 * 4 + 2] = v.z; w3r[c4 * 4 + 3] = v.w;
        }
    }
    float awr[16];
#pragma unroll
    for (int k = 0; k < 16; ++k) awr[k] = aw[k];
    float sa = 0.0f;
#pragma unroll
    for (int k = 0; k < 16; ++k) sa += awr[k];
    const float b1v = b1[r], b2v = b2[lane], b3v = b3[lane], abv = ab[0];
    const float c1 = (vec == 0) ? 16.0f : sa;
    const u16* pfb = pfh + (size_t)b * NPTS * 64;

    u64*   sv  = surv[wv];
    float* vb0 = vbuf[wv][0];
    float* vb1 = vbuf[wv][1];
    float* h10 = h1buf[wv][0];
    float* h11 = h1buf[wv][1];

#pragma unroll 1
    for (int j = wv; j < m; j += 4) {
        const int q = si[qs + j];
        float qx = cb[q * 3 + 0], qy = cb[q * 3 + 1], qz = cb[q * 3 + 2];
        float qsq = sq_np32(qx, qy, qz);

        // ---- PASS A: lane minima -> tau ----
        float dmin = 3.0e38f;
        if (stagedOK) {
#pragma unroll 1
            for (int p = lane; p < nBox; p += 64) {
                float4 c = bpts[p];
                float d2 = d2_ref(qx, qy, qz, qsq, c.x, c.y, c.z, c.w);
                dmin = fminf(dmin, d2);
            }
        } else {                               // rare: global box scan (R9)
#pragma unroll 1
            for (int cx = ax0; cx <= ax1; ++cx)
#pragma unroll 1
                for (int cy = ay0; cy <= ay1; ++cy) {
                    int base = (cx * 8 + cy) * 8;
                    int s = cs[base + az0], e = cs[base + az1 + 1];
                    for (int i0 = s; i0 < e; i0 += 64) {
                        int i = i0 + lane;
                        int ii = (i < e) ? i : (e - 1);
                        float4 c = sp[ii];
                        float d2 = d2_ref(qx, qy, qz, qsq, c.x, c.y, c.z, c.w);
                        if (i < e) dmin = fminf(dmin, d2);
                    }
                }
        }
        {   // wave bitonic sort-64 ascending
            float v = dmin;
#pragma unroll
            for (int k = 2; k <= 64; k <<= 1) {
#pragma unroll
                for (int j2 = k >> 1; j2 >= 1; j2 >>= 1) {
                    float o = __shfl_xor(v, j2, 64);
                    bool lo = (lane & j2) == 0;
                    bool up = (lane & k) == 0;
                    float mn = fminf(v, o), mx = fmaxf(v, o);
                    v = (lo == up) ? mn : mx;
                }
            }
            dmin = __shfl(v, 15, 64);          // 16th smallest lane-min
        }
        const float tau = dmin;                 // >= true 16th-NN d2

        // ---- PASS B: filter d2 <= tau ----
        float rr = sqrtf(tau + 1e-5f) + 1e-6f;
        int bx0 = max((int)floorf((qx - rr) * 8.0f), 0);
        int bx1 = min((int)floorf((qx + rr) * 8.0f), 7);
        int by0 = max((int)floorf((qy - rr) * 8.0f), 0);
        int by1 = min((int)floorf((qy + rr) * 8.0f), 7);
        int bz0 = max((int)floorf((qz - rr) * 8.0f), 0);
        int bz1 = min((int)floorf((qz + rr) * 8.0f), 7);
        // fast iff the rr box is contained in the staged box (wave-uniform)
        bool fast = stagedOK && bx0 >= ax0 && bx1 <= ax1 && by0 >= ay0 &&
                    by1 <= ay1 && bz0 >= az0 && bz1 <= az1;
        int cnt = 0;
        if (fast) {
#pragma unroll 1
            for (int p0 = 0; p0 < nBox; p0 += 64) {
                int p = p0 + lane;
                bool valid = (p < nBox);
                int pp = valid ? p : (nBox - 1);
                float4 c = bpts[pp];
                float d2 = d2_ref(qx, qy, qz, qsq, c.x, c.y, c.z, c.w);
                bool pass = valid && (d2 <= tau);
                u64 mask = __ballot(pass);
                if (pass) {
                    int pre = __builtin_amdgcn_mbcnt_hi((u32)(mask >> 32),
                              __builtin_amdgcn_mbcnt_lo((u32)mask, 0));
                    int pos = cnt + pre;
                    if (pos < SCAP)
                        sv[pos] = ((u64)fordkey(d2) << 32) | (u32)bidx[pp];
                }
                cnt += (int)__popcll(mask);
            }
        } else {                               // global rr-box scan (R9-exact)
#pragma unroll 1
            for (int cx = bx0; cx <= bx1; ++cx)
#pragma unroll 1
                for (int cy = by0; cy <= by1; ++cy) {
                    int base = (cx * 8 + cy) * 8;
                    int s = cs[base + bz0], e = cs[base + bz1 + 1];
                    for (int i0 = s; i0 < e; i0 += 64) {
                        int i = i0 + lane;
                        bool valid = (i < e);
                        int ii = valid ? i : (e - 1);
                        float4 c = sp[ii];
                        float d2 = d2_ref(qx, qy, qz, qsq, c.x, c.y, c.z, c.w);
                        bool pass = valid && (d2 <= tau);
                        u64 mask = __ballot(pass);
                        if (pass) {
                            int pre = __builtin_amdgcn_mbcnt_hi((u32)(mask >> 32),
                                      __builtin_amdgcn_mbcnt_lo((u32)mask, 0));
                            int pos = cnt + pre;
                            if (pos < SCAP)
                                sv[pos] = ((u64)fordkey(d2) << 32) | (u32)si[ii];
                        }
                        cnt += (int)__popcll(mask);
                    }
                }
        }
        __threadfence_block();                 // wave-local: writes -> reads

        // ---- exact top-16 by (d2bits, idx) ----
        int myidx = 0;
        if (cnt <= 64) {
            u64 key = (lane < cnt) ? sv[lane] : ~0ull;
#pragma unroll
            for (int k = 2; k <= 64; k <<= 1) {
#pragma unroll
                for (int j2 = k >> 1; j2 >= 1; j2 >>= 1) {
                    u64 o = shflxor64(key, j2);
                    bool lo = (lane & j2) == 0;
                    bool up = (lane & k) == 0;
                    bool takemin = (lo == up);
                    key = ((o < key) == takemin) ? o : key;
                }
            }
            myidx = (int)(u32)(key & 0xffffffffu);
        } else {
            int cc = cnt > SCAP ? SCAP : cnt;
            u64 a0 = (lane < cc) ? sv[lane] : ~0ull;
            u64 a1 = (64 + lane < cc) ? sv[64 + lane] : ~0ull;
            if (a1 < a0) { u64 tmp = a0; a0 = a1; a1 = tmp; }
#pragma unroll 1
            for (int rr2 = 0; rr2 < 16; ++rr2) {
                u64 mm = a0;
#pragma unroll
                for (int d = 1; d < 64; d <<= 1) {
                    u64 o = shflxor64(mm, d);
                    mm = (o < mm) ? o : mm;
                }
                if (a0 == mm) { a0 = a1; a1 = ~0ull; }
                if (lane == rr2) myidx = (int)(u32)(mm & 0xffffffffu);
            }
        }
        __threadfence_block();                 // sv reads done before next write

        // ---- MLP (R10-exact math; per-wave buffers) ----
        int myi = __shfl(myidx, lane & 15, 64);

        float pool = -3.0e38f, G1 = 0.0f, Ga = 0.0f;
#pragma unroll
        for (int k = 0; k < 16; ++k) {
            int nk = __shfl(myi, k, 64);
            float v = bf2f(pfb[nk * 64 + lane]);
            pool = fmaxf(pool, v);
            G1 += v;
            Ga = fmaf(awr[k], v, Ga);
        }
        vb0[lane] = G1;
        vb1[lane] = Ga;
        if (lane < 48) {
            int j1 = lane >> 4;
            int i0 = __shfl(myi, 0, 64);
            float rel  = cb[myi * 3 + j1] - cb[i0 * 3 + j1];
            float wrel = awr[lane & 15] * rel;
#pragma unroll
            for (int d = 1; d < 16; d <<= 1) {
                rel  += __shfl_xor(rel, d, 64);
                wrel += __shfl_xor(wrel, d, 64);
            }
            if ((lane & 15) == 0) { vb0[64 + j1] = rel; vb1[64 + j1] = wrel; }
        }
        if (lane == 0) { vb0[67] = 0.0f; vb1[67] = 0.0f; }
        __threadfence_block();

        float acc = c1 * b1v;
        {
            const float4* vp = (const float4*)((vec == 0) ? vb0 : vb1);
#pragma unroll
            for (int c4 = 0; c4 < 17; ++c4) {
                float4 g4 = vp[c4];
                acc = fmaf(g4.x, w1r[c4 * 4 + 0], acc);
                acc = fmaf(g4.y, w1r[c4 * 4 + 1], acc);
                acc = fmaf(g4.z, w1r[c4 * 4 + 2], acc);
                acc = fmaf(g4.w, w1r[c4 * 4 + 3], acc);
            }
        }
        ((vec == 0) ? h10 : h11)[r] = acc;
        __threadfence_block();

        float a0 = 16.0f * b2v, a1 = sa * b2v;
        {
            const float4* p0 = (const float4*)h10;
            const float4* p1 = (const float4*)h11;
#pragma unroll
            for (int c4 = 0; c4 < 8; ++c4) {
                float4 x0 = p0[c4], x1 = p1[c4];
                a0 = fmaf(x0.x, w2r[c4 * 4 + 0], a0);
                a0 = fmaf(x0.y, w2r[c4 * 4 + 1], a0);
                a0 = fmaf(x0.z, w2r[c4 * 4 + 2], a0);
                a0 = fmaf(x0.w, w2r[c4 * 4 + 3], a0);
                a1 = fmaf(x1.x, w2r[c4 * 4 + 0], a1);
                a1 = fmaf(x1.y, w2r[c4 * 4 + 1], a1);
                a1 = fmaf(x1.z, w2r[c4 * 4 + 2], a1);
                a1 = fmaf(x1.w, w2r[c4 * 4 + 3], a1);
            }
        }
        __threadfence_block();                 // vbuf reads retired
        vb0[lane] = a0;
        vb1[lane] = a1;
        __threadfence_block();

        float s1 = 16.0f * b3v, sA = sa * b3v;
        {
            const float4* p0 = (const float4*)vb0;
            const float4* p1 = (const float4*)vb1;
#pragma unroll
            for (int c4 = 0; c4 < 16; ++c4) {
                float4 x0 = p0[c4], x1 = p1[c4];
                s1 = fmaf(x0.x, w3r[c4 * 4 + 0], s1);
                s1 = fmaf(x0.y, w3r[c4 * 4 + 1], s1);
                s1 = fmaf(x0.z, w3r[c4 * 4 + 2], s1);
                s1 = fmaf(x0.w, w3r[c4 * 4 + 3], s1);
                sA = fmaf(x1.x, w3r[c4 * 4 + 0], sA);
                sA = fmaf(x1.y, w3r[c4 * 4 + 1], sA);
                sA = fmaf(x1.z, w3r[c4 * 4 + 2], sA);
                sA = fmaf(x1.w, w3r[c4 * 4 + 3], sA);
            }
        }
        float* op = out + ((size_t)b * NPTS + q) * 192;
        op[lane]       = s1;
        op[64 + lane]  = pool;
        op[128 + lane] = sA + abv;
        __threadfence_block();                 // before next query reuses buffers
    }
}

extern "C" void kernel_launch(void* const* d_in, const int* in_sizes, int n_in,
                              void* d_out, int out_size, void* d_ws, size_t ws_size,
                              hipStream_t stream) {
    const float* pf     = (const float*)d_in[0];
    const float* coords = (const float*)d_in[1];
    const float* w1     = (const float*)d_in[2];
    const float* b1     = (const float*)d_in[3];
    const float* w2     = (const float*)d_in[4];
    const float* b2     = (const float*)d_in[5];
    const float* w3     = (const float*)d_in[6];
    const float* b3     = (const float*)d_in[7];
    const float* aw     = (const float*)d_in[8];
    const float* ab     = (const float*)d_in[9];

    char* ws = (char*)d_ws;
    u16*    pfh        = (u16*)ws;                              // 2 MB
    float4* spts       = (float4*)(ws + (2 << 20));             // 256 KB
    int*    sidx       = (int*)(ws + (2 << 20) + (256 << 10));  // 64 KB
    int*    cellStart  = (int*)(ws + (2 << 20) + (320 << 10));  // 2*513*4 B
    int*    counts     = (int*)(ws + (2 << 20) + (328 << 10));  // 2*512*4 B
    int*    cellOffset = (int*)(ws + (2 << 20) + (336 << 10));  // 2*512*4 B
    float*  outp       = (float*)d_out;

    hipMemsetAsync(counts, 0, 2 * 512 * sizeof(int), stream);
    pack_count_kernel<<<4096, 256, 0, stream>>>(pf, coords, pfh, counts);
    scan_kernel<<<2, 512, 0, stream>>>(counts, cellStart, cellOffset);
    scatter_kernel<<<64, 256, 0, stream>>>(coords, cellOffset, spts, sidx);
    knnmlp_kernel<<<1024, 256, 0, stream>>>(coords, spts, sidx, cellStart, pfh,
                                            w1, b1, w2, b2, w3, b3, aw, ab, outp);
}

// Round 13
// 181.171 us; speedup vs baseline: 1.0152x; 1.0027x over previous
//
#include <hip/hip_runtime.h>
#include <stdint.h>

// ContinuousConvolution, MI355X gfx950. Round 13:
//  - 1 query per wave, 2 independent waves per 128-thr block (no block barriers),
//    8192 blocks -> ~16 waves/CU and fine-grained load balance.
//  - prep_kernel precomputes M = W3*W2*W1 (64x68) and e = W3(W2 b1 + b2) + b3:
//    the linear MLP collapses to one matvec on (Sum g, Sum aw*g).
//  - KNN body = R9-verified grid search (exact); sorted order + XCD swizzle.

typedef unsigned short u16;
typedef unsigned int   u32;
typedef unsigned long long u64;

#define NPTS  8192
#define KNB   16
#define SCAP  128

__device__ __forceinline__ float bf2f(u16 u) {
    union { u32 i; float f; } v; v.i = ((u32)u) << 16; return v.f;
}
__device__ __forceinline__ u16 f2bf(float f) {
    u32 x = __float_as_uint(f);
    return (u16)((x + 0x7FFFu + ((x >> 16) & 1u)) >> 16);  // RNE (lossless here)
}
__device__ __forceinline__ u32 fordkey(float f) {
    u32 u = __float_as_uint(f);
    return u ^ ((u32)((int)u >> 31) | 0x80000000u);
}
__device__ __forceinline__ u64 shflxor64(u64 v, int m) {
    int lo = __shfl_xor((int)(u32)v, m, 64);
    int hi = __shfl_xor((int)(u32)(v >> 32), m, 64);
    return ((u64)(u32)hi << 32) | (u32)lo;
}
// Reference-matching d2 (verified round 5): dot = Eigen FMA chain, rest strict.
__device__ __forceinline__ float sq_np32(float x, float y, float z) {
    return __fadd_rn(__fadd_rn(__fmul_rn(x, x), __fmul_rn(y, y)), __fmul_rn(z, z));
}
__device__ __forceinline__ float d2_ref(float qx, float qy, float qz, float qsq,
                                        float x, float y, float z, float sq) {
    float dot = fmaf(z, qz, fmaf(y, qy, __fmul_rn(x, qx)));
    return __fsub_rn(__fadd_rn(qsq, sq), __fmul_rn(2.0f, dot));
}
__device__ __forceinline__ int cellof(float v) {
    int c = (int)floorf(v * 8.0f);
    return c < 0 ? 0 : (c > 7 ? 7 : c);
}

// ---------------- Kernel 1: pack + count ----------------
__global__ __launch_bounds__(256) void pack_count_kernel(
    const float* __restrict__ pf, const float* __restrict__ coords,
    u16* __restrict__ pfh, int* __restrict__ counts) {
    int gid = blockIdx.x * 256 + threadIdx.x;     // 0..1048575
    pfh[gid] = f2bf(pf[gid]);
    if (gid < 2 * NPTS) {
        float x = coords[gid * 3 + 0];
        float y = coords[gid * 3 + 1];
        float z = coords[gid * 3 + 2];
        int b = gid >> 13;
        int cell = (cellof(x) * 8 + cellof(y)) * 8 + cellof(z);
        atomicAdd(&counts[b * 512 + cell], 1);
    }
}

// ---------------- Kernel 2: scan ----------------
__global__ __launch_bounds__(512) void scan_kernel(
    const int* __restrict__ counts, int* __restrict__ cellStart,
    int* __restrict__ cellOffset) {
    __shared__ int s[512];
    int b = blockIdx.x, t = threadIdx.x;
    int myc = counts[b * 512 + t];
    s[t] = myc; __syncthreads();
#pragma unroll
    for (int o = 1; o < 512; o <<= 1) {
        int v = (t >= o) ? s[t - o] : 0; __syncthreads();
        s[t] += v; __syncthreads();
    }
    int excl = s[t] - myc;
    cellStart[b * 513 + t] = excl;
    cellOffset[b * 512 + t] = excl;
    if (t == 511) cellStart[b * 513 + 512] = s[511];
}

// ---------------- Kernel 3: scatter ----------------
__global__ __launch_bounds__(256) void scatter_kernel(
    const float* __restrict__ coords, int* __restrict__ cellOffset,
    float4* __restrict__ spts, int* __restrict__ sidx) {
    int gid = blockIdx.x * 256 + threadIdx.x;     // 0..16383
    float x = coords[gid * 3 + 0];
    float y = coords[gid * 3 + 1];
    float z = coords[gid * 3 + 2];
    int b = gid >> 13, i = gid & (NPTS - 1);
    int cell = (cellof(x) * 8 + cellof(y)) * 8 + cellof(z);
    int pos = atomicAdd(&cellOffset[b * 512 + cell], 1);
    spts[b * NPTS + pos] = make_float4(x, y, z, sq_np32(x, y, z));
    sidx[b * NPTS + pos] = i;
}

// ---------------- Kernel 4: collapse weights ----------------
// M = W3*W2*W1 (64 x 68, col 67 = 0), E = W3*(W2*b1 + b2) + b3.
__global__ __launch_bounds__(64) void prep_kernel(
    const float* __restrict__ w1, const float* __restrict__ b1,
    const float* __restrict__ w2, const float* __restrict__ b2,
    const float* __restrict__ w3, const float* __restrict__ b3,
    float* __restrict__ M, float* __restrict__ E) {
    __shared__ float W1s[32 * 67];
    __shared__ float W2s[64 * 32];
    __shared__ float W3s[64 * 64];
    __shared__ float T[64][68];
    __shared__ float tb2[64];
    int t = threadIdx.x;                    // 0..63
    for (int i = t; i < 32 * 67; i += 64) W1s[i] = w1[i];
    for (int i = t; i < 64 * 32; i += 64) W2s[i] = w2[i];
    for (int i = t; i < 64 * 64; i += 64) W3s[i] = w3[i];
    __syncthreads();
    {
        float accb = 0.0f;
#pragma unroll
        for (int i = 0; i < 32; ++i) accb = fmaf(W2s[t * 32 + i], b1[i], accb);
        tb2[t] = accb + b2[t];
#pragma unroll 1
        for (int c = 0; c < 67; ++c) {
            float acc = 0.0f;
#pragma unroll
            for (int i = 0; i < 32; ++i)
                acc = fmaf(W2s[t * 32 + i], W1s[i * 67 + c], acc);
            T[t][c] = acc;
        }
        T[t][67] = 0.0f;
    }
    __syncthreads();
#pragma unroll 1
    for (int c = 0; c < 67; ++c) {
        float acc = 0.0f;
#pragma unroll
        for (int j = 0; j < 64; ++j)
            acc = fmaf(W3s[t * 64 + j], T[j][c], acc);
        M[t * 68 + c] = acc;
    }
    M[t * 68 + 67] = 0.0f;
    float e = 0.0f;
#pragma unroll
    for (int j = 0; j < 64; ++j) e = fmaf(W3s[t * 64 + j], tb2[j], e);
    E[t] = e + b3[t];
}

// ---------------- Kernel 5: fused knn + collapsed mlp ----------------
// 8192 blocks x 128 threads = 2 independent waves, 1 query per wave.
__global__ __launch_bounds__(128) void knnmlp_kernel(
    const float* __restrict__ coords, const float4* __restrict__ spts,
    const int* __restrict__ sidx, const int* __restrict__ cellStart,
    const u16* __restrict__ pfh, const float* __restrict__ M,
    const float* __restrict__ E, const float* __restrict__ aw,
    const float* __restrict__ ab, float* __restrict__ out) {

    __shared__ u64 surv[2][SCAP];
    __shared__ __attribute__((aligned(16))) float vb[2][2][68];

    const int lane = threadIdx.x & 63;
    const int wv   = threadIdx.x >> 6;
    // XCD chunk swizzle over sorted positions (grid 8192 = 8 x 1024)
    const int sblk = ((int)blockIdx.x & 7) * 1024 + ((int)blockIdx.x >> 3);
    const int pos  = sblk * 2 + wv;            // 0..16383 sorted position
    const int b    = pos >> 13;
    const int p    = pos & (NPTS - 1);
    const float*  cb = coords + (size_t)b * NPTS * 3;
    const float4* sp = spts + b * NPTS;
    const int*    si = sidx + b * NPTS;
    const int*    cs = cellStart + b * 513;
    u64* sv = surv[wv];

    const int q = si[p];
    float qx = cb[q * 3 + 0], qy = cb[q * 3 + 1], qz = cb[q * 3 + 2];
    float qsq = sq_np32(qx, qy, qz);
    int cqx = cellof(qx), cqy = cellof(qy), cqz = cellof(qz);

    // PASS A: lane-minima over 3^3 cell box -> conservative tau (R9-exact)
    int ax0 = max(cqx - 1, 0), ax1 = min(cqx + 1, 7);
    int ay0 = max(cqy - 1, 0), ay1 = min(cqy + 1, 7);
    int az0 = max(cqz - 1, 0), az1 = min(cqz + 1, 7);
    float dmin = 3.0e38f;
#pragma unroll 1
    for (int cx = ax0; cx <= ax1; ++cx)
#pragma unroll 1
        for (int cy = ay0; cy <= ay1; ++cy) {
            int base = (cx * 8 + cy) * 8;
            int s = cs[base + az0], e = cs[base + az1 + 1];
            for (int i0 = s; i0 < e; i0 += 64) {
                int i = i0 + lane;
                int ii = (i < e) ? i : (e - 1);
                float4 c = sp[ii];
                float d2 = d2_ref(qx, qy, qz, qsq, c.x, c.y, c.z, c.w);
                if (i < e) dmin = fminf(dmin, d2);
            }
        }
    {   // wave bitonic sort-64 ascending
        float v = dmin;
#pragma unroll
        for (int k = 2; k <= 64; k <<= 1) {
#pragma unroll
            for (int j2 = k >> 1; j2 >= 1; j2 >>= 1) {
                float o = __shfl_xor(v, j2, 64);
                bool lo = (lane & j2) == 0;
                bool up = (lane & k) == 0;
                float mn = fminf(v, o), mx = fmaxf(v, o);
                v = (lo == up) ? mn : mx;
            }
        }
        dmin = __shfl(v, 15, 64);              // 16th smallest lane-min
    }
    const float tau = dmin;                     // >= true 16th-NN d2

    // PASS B: wave-uniform filter scan over rr-box, d2 <= tau
    float rr = sqrtf(tau + 1e-5f) + 1e-6f;
    int bx0 = max((int)floorf((qx - rr) * 8.0f), 0);
    int bx1 = min((int)floorf((qx + rr) * 8.0f), 7);
    int by0 = max((int)floorf((qy - rr) * 8.0f), 0);
    int by1 = min((int)floorf((qy + rr) * 8.0f), 7);
    int bz0 = max((int)floorf((qz - rr) * 8.0f), 0);
    int bz1 = min((int)floorf((qz + rr) * 8.0f), 7);
    int cnt = 0;
#pragma unroll 1
    for (int cx = bx0; cx <= bx1; ++cx)
#pragma unroll 1
        for (int cy = by0; cy <= by1; ++cy) {
            int base = (cx * 8 + cy) * 8;
            int s = cs[base + bz0], e = cs[base + bz1 + 1];
            for (int i0 = s; i0 < e; i0 += 64) {
                int i = i0 + lane;
                bool valid = (i < e);
                int ii = valid ? i : (e - 1);
                float4 c = sp[ii];
                float d2 = d2_ref(qx, qy, qz, qsq, c.x, c.y, c.z, c.w);
                bool pass = valid && (d2 <= tau);
                u64 mask = __ballot(pass);
                if (pass) {
                    int pre = __builtin_amdgcn_mbcnt_hi((u32)(mask >> 32),
                              __builtin_amdgcn_mbcnt_lo((u32)mask, 0));
                    int pp = cnt + pre;
                    if (pp < SCAP)
                        sv[pp] = ((u64)fordkey(d2) << 32) | (u32)si[ii];
                }
                cnt += (int)__popcll(mask);
            }
        }
    __threadfence_block();

    // exact top-16 by (d2bits, idx)
    int myidx = 0;
    if (cnt <= 64) {
        u64 key = (lane < cnt) ? sv[lane] : ~0ull;
#pragma unroll
        for (int k = 2; k <= 64; k <<= 1) {
#pragma unroll
            for (int j2 = k >> 1; j2 >= 1; j2 >>= 1) {
                u64 o = shflxor64(key, j2);
                bool lo = (lane & j2) == 0;
                bool up = (lane & k) == 0;
                bool takemin = (lo == up);
                key = ((o < key) == takemin) ? o : key;
            }
        }
        myidx = (int)(u32)(key & 0xffffffffu);  // lanes 0..15 = top-16 asc
    } else {
        int cc = cnt > SCAP ? SCAP : cnt;
        u64 a0 = (lane < cc) ? sv[lane] : ~0ull;
        u64 a1 = (64 + lane < cc) ? sv[64 + lane] : ~0ull;
        if (a1 < a0) { u64 tmp = a0; a0 = a1; a1 = tmp; }
#pragma unroll 1
        for (int r2 = 0; r2 < 16; ++r2) {
            u64 mm = a0;
#pragma unroll
            for (int d = 1; d < 64; d <<= 1) {
                u64 o = shflxor64(mm, d);
                mm = (o < mm) ? o : mm;
            }
            if (a0 == mm) { a0 = a1; a1 = ~0ull; }
            if (lane == r2) myidx = (int)(u32)(mm & 0xffffffffu);
        }
    }

    __builtin_amdgcn_sched_barrier(0);          // keep mlp loads out of knn phase

    // ---------------- collapsed MLP ----------------
    float awr[16];
#pragma unroll
    for (int k = 0; k < 16; ++k) awr[k] = aw[k];
    float sa = 0.0f;
#pragma unroll
    for (int k = 0; k < 16; ++k) sa += awr[k];
    const float ev = E[lane], abv = ab[0];
    const u16* pfb = pfh + (size_t)b * NPTS * 64;

    float pool = -3.0e38f, G1 = 0.0f, Ga = 0.0f;
#pragma unroll
    for (int k = 0; k < 16; ++k) {
        int nk = __shfl(myidx, k, 64);
        float v = bf2f(pfb[nk * 64 + lane]);
        pool = fmaxf(pool, v);
        G1 += v;
        Ga = fmaf(awr[k], v, Ga);
    }
    float* v0 = vb[wv][0];
    float* v1 = vb[wv][1];
    v0[lane] = G1;
    v1[lane] = Ga;
    if (lane < 48) {
        int j1 = lane >> 4;
        int nk2 = __shfl(myidx, lane & 15, 64);
        int i0  = __shfl(myidx, 0, 64);
        float rel  = cb[nk2 * 3 + j1] - cb[i0 * 3 + j1];
        float wrel = awr[lane & 15] * rel;
#pragma unroll
        for (int d = 1; d < 16; d <<= 1) {
            rel  += __shfl_xor(rel, d, 64);
            wrel += __shfl_xor(wrel, d, 64);
        }
        if ((lane & 15) == 0) { v0[64 + j1] = rel; v1[64 + j1] = wrel; }
    }
    if (lane == 0) { v0[67] = 0.0f; v1[67] = 0.0f; }
    __threadfence_block();

    // one matvec on both vectors: lane = output channel, M row in registers
    float s1 = 16.0f * ev, sA = sa * ev;
    {
        const float4* mp = (const float4*)(M + lane * 68);   // 17 aligned float4
        const float4* p0 = (const float4*)v0;
        const float4* p1 = (const float4*)v1;
#pragma unroll
        for (int c4 = 0; c4 < 17; ++c4) {
            float4 mr = mp[c4];
            float4 x0 = p0[c4], x1 = p1[c4];
            s1 = fmaf(x0.x, mr.x, s1); s1 = fmaf(x0.y, mr.y, s1);
            s1 = fmaf(x0.z, mr.z, s1); s1 = fmaf(x0.w, mr.w, s1);
            sA = fmaf(x1.x, mr.x, sA); sA = fmaf(x1.y, mr.y, sA);
            sA = fmaf(x1.z, mr.z, sA); sA = fmaf(x1.w, mr.w, sA);
        }
    }
    float* op = out + ((size_t)b * NPTS + q) * 192;
    op[lane]       = s1;
    op[64 + lane]  = pool;
    op[128 + lane] = sA + abv;
}

extern "C" void kernel_launch(void* const* d_in, const int* in_sizes, int n_in,
                              void* d_out, int out_size, void* d_ws, size_t ws_size,
                              hipStream_t stream) {
    const float* pf     = (const float*)d_in[0];
    const float* coords = (const float*)d_in[1];
    const float* w1     = (const float*)d_in[2];
    const float* b1     = (const float*)d_in[3];
    const float* w2     = (const float*)d_in[4];
    const float* b2     = (const float*)d_in[5];
    const float* w3     = (const float*)d_in[6];
    const float* b3     = (const float*)d_in[7];
    const float* aw     = (const float*)d_in[8];
    const float* ab     = (const float*)d_in[9];

    char* ws = (char*)d_ws;
    u16*    pfh        = (u16*)ws;                              // 2 MB
    float4* spts       = (float4*)(ws + (2 << 20));             // 256 KB
    int*    sidx       = (int*)(ws + (2 << 20) + (256 << 10));  // 64 KB
    int*    cellStart  = (int*)(ws + (2 << 20) + (320 << 10));  // 2*513*4 B
    int*    counts     = (int*)(ws + (2 << 20) + (328 << 10));  // 2*512*4 B
    int*    cellOffset = (int*)(ws + (2 << 20) + (336 << 10));  // 2*512*4 B
    float*  Mw         = (float*)(ws + (2 << 20) + (344 << 10)); // 64*68*4 B
    float*  Ew         = (float*)(ws + (2 << 20) + (364 << 10)); // 256 B
    float*  outp       = (float*)d_out;

    hipMemsetAsync(counts, 0, 2 * 512 * sizeof(int), stream);
    pack_count_kernel<<<4096, 256, 0, stream>>>(pf, coords, pfh, counts);
    scan_kernel<<<2, 512, 0, stream>>>(counts, cellStart, cellOffset);
    scatter_kernel<<<64, 256, 0, stream>>>(coords, cellOffset, spts, sidx);
    prep_kernel<<<1, 64, 0, stream>>>(w1, b1, w2, b2, w3, b3, Mw, Ew);
    knnmlp_kernel<<<8192, 128, 0, stream>>>(coords, spts, sidx, cellStart, pfh,
                                            Mw, Ew, aw, ab, outp);
}

// Round 14
// 155.423 us; speedup vs baseline: 1.1834x; 1.1657x over previous
//
#include <hip/hip_runtime.h>
#include <stdint.h>

// ContinuousConvolution, MI355X gfx950. Round 14: parallelize prep_kernel.
// R13's prep was one 64-thread wave of dependent FMA chains (58 us, VALUBusy
// 0.01%). Now 256 threads, element-parallel over the 64x67 outputs with
// per-element accumulation order IDENTICAL to R13 -> bit-identical M,E,output.
// knnmlp + builds unchanged from R13.

typedef unsigned short u16;
typedef unsigned int   u32;
typedef unsigned long long u64;

#define NPTS  8192
#define KNB   16
#define SCAP  128

__device__ __forceinline__ float bf2f(u16 u) {
    union { u32 i; float f; } v; v.i = ((u32)u) << 16; return v.f;
}
__device__ __forceinline__ u16 f2bf(float f) {
    u32 x = __float_as_uint(f);
    return (u16)((x + 0x7FFFu + ((x >> 16) & 1u)) >> 16);  // RNE (lossless here)
}
__device__ __forceinline__ u32 fordkey(float f) {
    u32 u = __float_as_uint(f);
    return u ^ ((u32)((int)u >> 31) | 0x80000000u);
}
__device__ __forceinline__ u64 shflxor64(u64 v, int m) {
    int lo = __shfl_xor((int)(u32)v, m, 64);
    int hi = __shfl_xor((int)(u32)(v >> 32), m, 64);
    return ((u64)(u32)hi << 32) | (u32)lo;
}
// Reference-matching d2 (verified round 5): dot = Eigen FMA chain, rest strict.
__device__ __forceinline__ float sq_np32(float x, float y, float z) {
    return __fadd_rn(__fadd_rn(__fmul_rn(x, x), __fmul_rn(y, y)), __fmul_rn(z, z));
}
__device__ __forceinline__ float d2_ref(float qx, float qy, float qz, float qsq,
                                        float x, float y, float z, float sq) {
    float dot = fmaf(z, qz, fmaf(y, qy, __fmul_rn(x, qx)));
    return __fsub_rn(__fadd_rn(qsq, sq), __fmul_rn(2.0f, dot));
}
__device__ __forceinline__ int cellof(float v) {
    int c = (int)floorf(v * 8.0f);
    return c < 0 ? 0 : (c > 7 ? 7 : c);
}

// ---------------- Kernel 1: pack + count ----------------
__global__ __launch_bounds__(256) void pack_count_kernel(
    const float* __restrict__ pf, const float* __restrict__ coords,
    u16* __restrict__ pfh, int* __restrict__ counts) {
    int gid = blockIdx.x * 256 + threadIdx.x;     // 0..1048575
    pfh[gid] = f2bf(pf[gid]);
    if (gid < 2 * NPTS) {
        float x = coords[gid * 3 + 0];
        float y = coords[gid * 3 + 1];
        float z = coords[gid * 3 + 2];
        int b = gid >> 13;
        int cell = (cellof(x) * 8 + cellof(y)) * 8 + cellof(z);
        atomicAdd(&counts[b * 512 + cell], 1);
    }
}

// ---------------- Kernel 2: scan ----------------
__global__ __launch_bounds__(512) void scan_kernel(
    const int* __restrict__ counts, int* __restrict__ cellStart,
    int* __restrict__ cellOffset) {
    __shared__ int s[512];
    int b = blockIdx.x, t = threadIdx.x;
    int myc = counts[b * 512 + t];
    s[t] = myc; __syncthreads();
#pragma unroll
    for (int o = 1; o < 512; o <<= 1) {
        int v = (t >= o) ? s[t - o] : 0; __syncthreads();
        s[t] += v; __syncthreads();
    }
    int excl = s[t] - myc;
    cellStart[b * 513 + t] = excl;
    cellOffset[b * 512 + t] = excl;
    if (t == 511) cellStart[b * 513 + 512] = s[511];
}

// ---------------- Kernel 3: scatter ----------------
__global__ __launch_bounds__(256) void scatter_kernel(
    const float* __restrict__ coords, int* __restrict__ cellOffset,
    float4* __restrict__ spts, int* __restrict__ sidx) {
    int gid = blockIdx.x * 256 + threadIdx.x;     // 0..16383
    float x = coords[gid * 3 + 0];
    float y = coords[gid * 3 + 1];
    float z = coords[gid * 3 + 2];
    int b = gid >> 13, i = gid & (NPTS - 1);
    int cell = (cellof(x) * 8 + cellof(y)) * 8 + cellof(z);
    int pos = atomicAdd(&cellOffset[b * 512 + cell], 1);
    spts[b * NPTS + pos] = make_float4(x, y, z, sq_np32(x, y, z));
    sidx[b * NPTS + pos] = i;
}

// ---------------- Kernel 4: collapse weights (parallel) ----------------
// M = W3*W2*W1 (64 x 68, col 67 = 0), E = W3*(W2*b1 + b2) + b3.
// 256 threads, element-parallel; per-element accum order == R13 (bit-identical).
__global__ __launch_bounds__(256) void prep_kernel(
    const float* __restrict__ w1, const float* __restrict__ b1,
    const float* __restrict__ w2, const float* __restrict__ b2,
    const float* __restrict__ w3, const float* __restrict__ b3,
    float* __restrict__ M, float* __restrict__ E) {
    __shared__ float W1s[32 * 67];
    __shared__ float W2s[64 * 32];
    __shared__ float W3s[64 * 64];
    __shared__ float T[64][68];
    __shared__ float tb2[64];
    int t = threadIdx.x;                    // 0..255
    for (int i = t; i < 32 * 67; i += 256) W1s[i] = w1[i];
    for (int i = t; i < 64 * 32; i += 256) W2s[i] = w2[i];
    for (int i = t; i < 64 * 64; i += 256) W3s[i] = w3[i];
    __syncthreads();
#pragma unroll 1
    for (int e = t; e < 64 * 67; e += 256) {
        int row = e / 67, c = e - row * 67;
        float acc = 0.0f;
#pragma unroll
        for (int i = 0; i < 32; ++i)
            acc = fmaf(W2s[row * 32 + i], W1s[i * 67 + c], acc);
        T[row][c] = acc;
    }
    if (t < 64) {
        float accb = 0.0f;
#pragma unroll
        for (int i = 0; i < 32; ++i) accb = fmaf(W2s[t * 32 + i], b1[i], accb);
        tb2[t] = accb + b2[t];
        T[t][67] = 0.0f;
    }
    __syncthreads();
#pragma unroll 1
    for (int e = t; e < 64 * 67; e += 256) {
        int row = e / 67, c = e - row * 67;
        float acc = 0.0f;
#pragma unroll
        for (int j = 0; j < 64; ++j)
            acc = fmaf(W3s[row * 64 + j], T[j][c], acc);
        M[row * 68 + c] = acc;
    }
    if (t < 64) {
        M[t * 68 + 67] = 0.0f;
        float e2 = 0.0f;
#pragma unroll
        for (int j = 0; j < 64; ++j) e2 = fmaf(W3s[t * 64 + j], tb2[j], e2);
        E[t] = e2 + b3[t];
    }
}

// ---------------- Kernel 5: fused knn + collapsed mlp (unchanged R13) --------
// 8192 blocks x 128 threads = 2 independent waves, 1 query per wave.
__global__ __launch_bounds__(128) void knnmlp_kernel(
    const float* __restrict__ coords, const float4* __restrict__ spts,
    const int* __restrict__ sidx, const int* __restrict__ cellStart,
    const u16* __restrict__ pfh, const float* __restrict__ M,
    const float* __restrict__ E, const float* __restrict__ aw,
    const float* __restrict__ ab, float* __restrict__ out) {

    __shared__ u64 surv[2][SCAP];
    __shared__ __attribute__((aligned(16))) float vb[2][2][68];

    const int lane = threadIdx.x & 63;
    const int wv   = threadIdx.x >> 6;
    // XCD chunk swizzle over sorted positions (grid 8192 = 8 x 1024)
    const int sblk = ((int)blockIdx.x & 7) * 1024 + ((int)blockIdx.x >> 3);
    const int pos  = sblk * 2 + wv;            // 0..16383 sorted position
    const int b    = pos >> 13;
    const int p    = pos & (NPTS - 1);
    const float*  cb = coords + (size_t)b * NPTS * 3;
    const float4* sp = spts + b * NPTS;
    const int*    si = sidx + b * NPTS;
    const int*    cs = cellStart + b * 513;
    u64* sv = surv[wv];

    const int q = si[p];
    float qx = cb[q * 3 + 0], qy = cb[q * 3 + 1], qz = cb[q * 3 + 2];
    float qsq = sq_np32(qx, qy, qz);
    int cqx = cellof(qx), cqy = cellof(qy), cqz = cellof(qz);

    // PASS A: lane-minima over 3^3 cell box -> conservative tau (R9-exact)
    int ax0 = max(cqx - 1, 0), ax1 = min(cqx + 1, 7);
    int ay0 = max(cqy - 1, 0), ay1 = min(cqy + 1, 7);
    int az0 = max(cqz - 1, 0), az1 = min(cqz + 1, 7);
    float dmin = 3.0e38f;
#pragma unroll 1
    for (int cx = ax0; cx <= ax1; ++cx)
#pragma unroll 1
        for (int cy = ay0; cy <= ay1; ++cy) {
            int base = (cx * 8 + cy) * 8;
            int s = cs[base + az0], e = cs[base + az1 + 1];
            for (int i0 = s; i0 < e; i0 += 64) {
                int i = i0 + lane;
                int ii = (i < e) ? i : (e - 1);
                float4 c = sp[ii];
                float d2 = d2_ref(qx, qy, qz, qsq, c.x, c.y, c.z, c.w);
                if (i < e) dmin = fminf(dmin, d2);
            }
        }
    {   // wave bitonic sort-64 ascending
        float v = dmin;
#pragma unroll
        for (int k = 2; k <= 64; k <<= 1) {
#pragma unroll
            for (int j2 = k >> 1; j2 >= 1; j2 >>= 1) {
                float o = __shfl_xor(v, j2, 64);
                bool lo = (lane & j2) == 0;
                bool up = (lane & k) == 0;
                float mn = fminf(v, o), mx = fmaxf(v, o);
                v = (lo == up) ? mn : mx;
            }
        }
        dmin = __shfl(v, 15, 64);              // 16th smallest lane-min
    }
    const float tau = dmin;                     // >= true 16th-NN d2

    // PASS B: wave-uniform filter scan over rr-box, d2 <= tau
    float rr = sqrtf(tau + 1e-5f) + 1e-6f;
    int bx0 = max((int)floorf((qx - rr) * 8.0f), 0);
    int bx1 = min((int)floorf((qx + rr) * 8.0f), 7);
    int by0 = max((int)floorf((qy - rr) * 8.0f), 0);
    int by1 = min((int)floorf((qy + rr) * 8.0f), 7);
    int bz0 = max((int)floorf((qz - rr) * 8.0f), 0);
    int bz1 = min((int)floorf((qz + rr) * 8.0f), 7);
    int cnt = 0;
#pragma unroll 1
    for (int cx = bx0; cx <= bx1; ++cx)
#pragma unroll 1
        for (int cy = by0; cy <= by1; ++cy) {
            int base = (cx * 8 + cy) * 8;
            int s = cs[base + bz0], e = cs[base + bz1 + 1];
            for (int i0 = s; i0 < e; i0 += 64) {
                int i = i0 + lane;
                bool valid = (i < e);
                int ii = valid ? i : (e - 1);
                float4 c = sp[ii];
                float d2 = d2_ref(qx, qy, qz, qsq, c.x, c.y, c.z, c.w);
                bool pass = valid && (d2 <= tau);
                u64 mask = __ballot(pass);
                if (pass) {
                    int pre = __builtin_amdgcn_mbcnt_hi((u32)(mask >> 32),
                              __builtin_amdgcn_mbcnt_lo((u32)mask, 0));
                    int pp = cnt + pre;
                    if (pp < SCAP)
                        sv[pp] = ((u64)fordkey(d2) << 32) | (u32)si[ii];
                }
                cnt += (int)__popcll(mask);
            }
        }
    __threadfence_block();

    // exact top-16 by (d2bits, idx)
    int myidx = 0;
    if (cnt <= 64) {
        u64 key = (lane < cnt) ? sv[lane] : ~0ull;
#pragma unroll
        for (int k = 2; k <= 64; k <<= 1) {
#pragma unroll
            for (int j2 = k >> 1; j2 >= 1; j2 >>= 1) {
                u64 o = shflxor64(key, j2);
                bool lo = (lane & j2) == 0;
                bool up = (lane & k) == 0;
                bool takemin = (lo == up);
                key = ((o < key) == takemin) ? o : key;
            }
        }
        myidx = (int)(u32)(key & 0xffffffffu);  // lanes 0..15 = top-16 asc
    } else {
        int cc = cnt > SCAP ? SCAP : cnt;
        u64 a0 = (lane < cc) ? sv[lane] : ~0ull;
        u64 a1 = (64 + lane < cc) ? sv[64 + lane] : ~0ull;
        if (a1 < a0) { u64 tmp = a0; a0 = a1; a1 = tmp; }
#pragma unroll 1
        for (int r2 = 0; r2 < 16; ++r2) {
            u64 mm = a0;
#pragma unroll
            for (int d = 1; d < 64; d <<= 1) {
                u64 o = shflxor64(mm, d);
                mm = (o < mm) ? o : mm;
            }
            if (a0 == mm) { a0 = a1; a1 = ~0ull; }
            if (lane == r2) myidx = (int)(u32)(mm & 0xffffffffu);
        }
    }

    __builtin_amdgcn_sched_barrier(0);          // keep mlp loads out of knn phase

    // ---------------- collapsed MLP ----------------
    float awr[16];
#pragma unroll
    for (int k = 0; k < 16; ++k) awr[k] = aw[k];
    float sa = 0.0f;
#pragma unroll
    for (int k = 0; k < 16; ++k) sa += awr[k];
    const float ev = E[lane], abv = ab[0];
    const u16* pfb = pfh + (size_t)b * NPTS * 64;

    float pool = -3.0e38f, G1 = 0.0f, Ga = 0.0f;
#pragma unroll
    for (int k = 0; k < 16; ++k) {
        int nk = __shfl(myidx, k, 64);
        float v = bf2f(pfb[nk * 64 + lane]);
        pool = fmaxf(pool, v);
        G1 += v;
        Ga = fmaf(awr[k], v, Ga);
    }
    float* v0 = vb[wv][0];
    float* v1 = vb[wv][1];
    v0[lane] = G1;
    v1[lane] = Ga;
    if (lane < 48) {
        int j1 = lane >> 4;
        int nk2 = __shfl(myidx, lane & 15, 64);
        int i0  = __shfl(myidx, 0, 64);
        float rel  = cb[nk2 * 3 + j1] - cb[i0 * 3 + j1];
        float wrel = awr[lane & 15] * rel;
#pragma unroll
        for (int d = 1; d < 16; d <<= 1) {
            rel  += __shfl_xor(rel, d, 64);
            wrel += __shfl_xor(wrel, d, 64);
        }
        if ((lane & 15) == 0) { v0[64 + j1] = rel; v1[64 + j1] = wrel; }
    }
    if (lane == 0) { v0[67] = 0.0f; v1[67] = 0.0f; }
    __threadfence_block();

    // one matvec on both vectors: lane = output channel, M row in registers
    float s1 = 16.0f * ev, sA = sa * ev;
    {
        const float4* mp = (const float4*)(M + lane * 68);   // 17 aligned float4
        const float4* p0 = (const float4*)v0;
        const float4* p1 = (const float4*)v1;
#pragma unroll
        for (int c4 = 0; c4 < 17; ++c4) {
            float4 mr = mp[c4];
            float4 x0 = p0[c4], x1 = p1[c4];
            s1 = fmaf(x0.x, mr.x, s1); s1 = fmaf(x0.y, mr.y, s1);
            s1 = fmaf(x0.z, mr.z, s1); s1 = fmaf(x0.w, mr.w, s1);
            sA = fmaf(x1.x, mr.x, sA); sA = fmaf(x1.y, mr.y, sA);
            sA = fmaf(x1.z, mr.z, sA); sA = fmaf(x1.w, mr.w, sA);
        }
    }
    float* op = out + ((size_t)b * NPTS + q) * 192;
    op[lane]       = s1;
    op[64 + lane]  = pool;
    op[128 + lane] = sA + abv;
}

extern "C" void kernel_launch(void* const* d_in, const int* in_sizes, int n_in,
                              void* d_out, int out_size, void* d_ws, size_t ws_size,
                              hipStream_t stream) {
    const float* pf     = (const float*)d_in[0];
    const float* coords = (const float*)d_in[1];
    const float* w1     = (const float*)d_in[2];
    const float* b1     = (const float*)d_in[3];
    const float* w2     = (const float*)d_in[4];
    const float* b2     = (const float*)d_in[5];
    const float* w3     = (const float*)d_in[6];
    const float* b3     = (const float*)d_in[7];
    const float* aw     = (const float*)d_in[8];
    const float* ab     = (const float*)d_in[9];

    char* ws = (char*)d_ws;
    u16*    pfh        = (u16*)ws;                              // 2 MB
    float4* spts       = (float4*)(ws + (2 << 20));             // 256 KB
    int*    sidx       = (int*)(ws + (2 << 20) + (256 << 10));  // 64 KB
    int*    cellStart  = (int*)(ws + (2 << 20) + (320 << 10));  // 2*513*4 B
    int*    counts     = (int*)(ws + (2 << 20) + (328 << 10));  // 2*512*4 B
    int*    cellOffset = (int*)(ws + (2 << 20) + (336 << 10));  // 2*512*4 B
    float*  Mw         = (float*)(ws + (2 << 20) + (344 << 10)); // 64*68*4 B
    float*  Ew         = (float*)(ws + (2 << 20) + (364 << 10)); // 256 B
    float*  outp       = (float*)d_out;

    hipMemsetAsync(counts, 0, 2 * 512 * sizeof(int), stream);
    pack_count_kernel<<<4096, 256, 0, stream>>>(pf, coords, pfh, counts);
    scan_kernel<<<2, 512, 0, stream>>>(counts, cellStart, cellOffset);
    scatter_kernel<<<64, 256, 0, stream>>>(coords, cellOffset, spts, sidx);
    prep_kernel<<<1, 256, 0, stream>>>(w1, b1, w2, b2, w3, b3, Mw, Ew);
    knnmlp_kernel<<<8192, 128, 0, stream>>>(coords, spts, sidx, cellStart, pfh,
                                            Mw, Ew, aw, ab, outp);
}